// Round 15
// baseline (118.882 us; speedup 1.0000x reference)
//
#include <hip/hip_runtime.h>

namespace {

typedef _Float16 half8 __attribute__((ext_vector_type(8)));
typedef float f32x16 __attribute__((ext_vector_type(16)));

constexpr int Bb = 4, Nn = 8192, KNB = 6;
constexpr int KSLAB = 512;                   // knn slab points (8 KB)
constexpr int KCAP = 64;                     // knn candidate slots per query
constexpr int KNN_BLOCKS = Nn / 32;          // 256 (32 queries per block, 8 per wave)
constexpr int CH_BLOCKS = 1024;              // 8 bd * 8 eighths * 16 qb(512 queries)
constexpr int CH_CHUNK = 1024;               // points per chamfer block
constexpr int TAIL_BLOCKS = 128;

// XOR bank swizzle: bijective, even bank-group spread for writes (p=4t+k),
// chamfer reads (p=32tt+l) and knn reads (p=64jj+c).  group(slot)=slot mod 8.
#define SWZ(p) ((p) ^ ((((p) >> 3) & 7)))

union SMemU {
    half8 aF[CH_CHUNK];                      // 16 KB chamfer frags (swizzled)
    struct {
        float4 sp4[KSLAB];                   // 8 KB (swizzled)
        unsigned long long cand[32][KCAP];   // 16 KB
        int cnt[32];
        float part[32];
    } knn;                                   // ~24.3 KB
};

__device__ inline unsigned ordkey(float f) {
    unsigned b = __float_as_uint(f);
    return b ^ (unsigned)(((int)b >> 31) | 0x80000000);
}

__device__ inline half8 zero8() {
    half8 v;
    #pragma unroll
    for (int i = 0; i < 8; ++i) v[i] = (_Float16)0;
    return v;
}

// Consistent single-f16 scheme (kg0 slots only; kg1 lanes zero on B side):
//   acc = -p̂·q̂ + |p̂|²/2 ; d2 = |q̂|² + 2·acc = |q̂-p̂|² ± ~7e-6 (clamped >= 0)
__device__ inline half8 a_frag(float x, float y, float z) {
    _Float16 hx = (_Float16)x, hy = (_Float16)y, hz = (_Float16)z;
    const float xr = (float)hx, yr = (float)hy, zr = (float)hz;
    const float pp5 = 0.5f * (xr * xr + yr * yr + zr * zr);
    _Float16 ph = (_Float16)pp5, pl = (_Float16)(pp5 - (float)ph);
    half8 v;
    v[0] = -hx; v[1] = -hy; v[2] = -hz; v[3] = ph; v[4] = pl;
    v[5] = (_Float16)0; v[6] = (_Float16)0; v[7] = (_Float16)0;
    return v;
}
__device__ inline half8 b_frag(float x, float y, float z) {
    _Float16 hx = (_Float16)x, hy = (_Float16)y, hz = (_Float16)z;
    half8 v;
    v[0] = hx; v[1] = hy; v[2] = hz; v[3] = (_Float16)1; v[4] = (_Float16)1;
    v[5] = (_Float16)0; v[6] = (_Float16)0; v[7] = (_Float16)0;
    return v;
}

// ---------------- init: mins -> +inf, accumulators -> 0 ----------------
__global__ void init_ws_kernel(unsigned* __restrict__ minArr, float* __restrict__ acc) {
    int i = blockIdx.x * blockDim.x + threadIdx.x;
    if (i < 2 * Bb * Nn) minArr[i] = 0x7f800000u;
    if (i < 8) acc[i] = 0.0f;
}

// ------- fat kernel: knn blocks [0,256) + chamfer-mfma eighth-blocks [256,1280) ----
__global__ __launch_bounds__(256, 6) void fat_kernel(
    const float* __restrict__ disp, const float* __restrict__ tmpl,
    const float* __restrict__ targ, unsigned* __restrict__ outMin,
    float* __restrict__ acc) {
    __shared__ SMemU sm;
    const int tid = threadIdx.x;

    if (blockIdx.x >= KNN_BLOCKS) {
        // ===== chamfer via MFMA: 512 queries (4 groups/wave), 1024 points per block ====
        const int cb = (int)blockIdx.x - KNN_BLOCKS;   // 0..1023
        const int qbase = (cb & 15) * 512;
        const int eighth = (cb >> 4) & 7;
        const int bd = cb >> 7;                        // 0..7
        const int dir = bd & 1, b = bd >> 1;
        const int lane = tid & 63, w = tid >> 6;
        const int l31 = lane & 31, kg = lane >> 5;

        float qq[4];
        half8 Bf[4];
        #pragma unroll
        for (int j = 0; j < 4; ++j) {
            const int q = qbase + w * 128 + j * 32 + l31;
            const long e = ((long)b * Nn + q) * 3;
            float x, y, z;
            if (dir == 0) {   // queries = pred
                x = tmpl[e] + disp[e]; y = tmpl[e+1] + disp[e+1]; z = tmpl[e+2] + disp[e+2];
            } else {          // queries = targ
                x = targ[e]; y = targ[e+1]; z = targ[e+2];
            }
            _Float16 hx = (_Float16)x, hy = (_Float16)y, hz = (_Float16)z;
            const float xr = (float)hx, yr = (float)hy, zr = (float)hz;
            qq[j] = xr * xr + yr * yr + zr * zr;
            Bf[j] = (kg == 0) ? b_frag(x, y, z) : zero8();
        }

        float run[4] = {1e38f, 1e38f, 1e38f, 1e38f};
        const f32x16 zc = {0.f, 0.f, 0.f, 0.f, 0.f, 0.f, 0.f, 0.f,
                           0.f, 0.f, 0.f, 0.f, 0.f, 0.f, 0.f, 0.f};

        {
            const int pbase = eighth * CH_CHUNK;
            {
                // thread stages 4 consecutive points via 3x float4; swizzled LDS write
                const long fbase = ((long)b * Nn + pbase) * 3;   // float4-aligned
                const float4* s4 = (const float4*)((dir == 0 ? targ : tmpl) + fbase);
                float4 t0 = s4[tid * 3 + 0], t1 = s4[tid * 3 + 1], t2 = s4[tid * 3 + 2];
                if (dir == 1) {   // points = pred = tmpl + disp
                    const float4* d4 = (const float4*)(disp + fbase);
                    float4 u0 = d4[tid * 3 + 0], u1 = d4[tid * 3 + 1], u2 = d4[tid * 3 + 2];
                    t0.x += u0.x; t0.y += u0.y; t0.z += u0.z; t0.w += u0.w;
                    t1.x += u1.x; t1.y += u1.y; t1.z += u1.z; t1.w += u1.w;
                    t2.x += u2.x; t2.y += u2.y; t2.z += u2.z; t2.w += u2.w;
                }
                const int p0 = tid * 4;
                sm.aF[SWZ(p0 + 0)] = a_frag(t0.x, t0.y, t0.z);
                sm.aF[SWZ(p0 + 1)] = a_frag(t0.w, t1.x, t1.y);
                sm.aF[SWZ(p0 + 2)] = a_frag(t1.z, t1.w, t2.x);
                sm.aF[SWZ(p0 + 3)] = a_frag(t2.y, t2.z, t2.w);
            }
            __syncthreads();
            #pragma unroll 4
            for (int tt = 0; tt < 32; ++tt) {
                const int pr = tt * 32 + l31;
                const half8 a = sm.aF[SWZ(pr)];   // lanes l,l+32 broadcast (x0 on kg1)
                #pragma unroll
                for (int j = 0; j < 4; ++j) {
                    f32x16 c = __builtin_amdgcn_mfma_f32_32x32x16_f16(a, Bf[j], zc, 0, 0, 0);
                    #pragma unroll
                    for (int r = 0; r < 16; r += 2)
                        run[j] = fminf(run[j], fminf(c[r], c[r + 1]));  // -> v_min3_f32
                }
            }
        }

        #pragma unroll
        for (int j = 0; j < 4; ++j)
            run[j] = fminf(run[j], __shfl_xor(run[j], 32, 64));
        if (lane < 32) {
            const long base = ((long)dir * Bb + b) * Nn;
            #pragma unroll
            for (int j = 0; j < 4; ++j) {
                const int q = qbase + w * 128 + j * 32 + l31;
                const float d2 = fmaxf(fmaf(2.0f, run[j], qq[j]), 0.0f);
                atomicMin(&outMin[base + q], __float_as_uint(d2));
            }
        }
    } else {
        // ================= knn + smooth: 32 queries/block, 8 per wave =================
        const int kb = blockIdx.x;
        const int lane = tid & 63;
        const int wid = tid >> 6;
        const int c = lane;
        const int cs = c ^ (c >> 3);               // swizzled lane base: slot = jj*64 + cs

        const int qbase = kb * 32 + wid * 8;
        float axq[8], ayq[8], azq[8];
        #pragma unroll
        for (int i = 0; i < 8; ++i) {
            axq[i] = -tmpl[(qbase + i) * 3 + 0];
            ayq[i] = -tmpl[(qbase + i) * 3 + 1];
            azq[i] = -tmpl[(qbase + i) * 3 + 2];
        }
        const float INFf = __uint_as_float(0x7f800000u);

        if (tid < 32) sm.knn.cnt[tid] = 0;

        float cm[8];
        #pragma unroll
        for (int i = 0; i < 8; ++i) cm[i] = INFf;

        const float4* t4 = (const float4*)tmpl;   // template[0]

        for (int slab = 0; slab < Nn / KSLAB; ++slab) {
            __syncthreads();
            if (tid < 128) {   // 128 threads x 4 points = 512-point slab
                float4 t0 = t4[384 * slab + tid * 3 + 0];
                float4 t1 = t4[384 * slab + tid * 3 + 1];
                float4 t2 = t4[384 * slab + tid * 3 + 2];
                const int p0 = tid * 4;
                sm.knn.sp4[SWZ(p0 + 0)] = make_float4(t0.x, t0.y, t0.z,
                    0.5f * (t0.x * t0.x + t0.y * t0.y + t0.z * t0.z));
                sm.knn.sp4[SWZ(p0 + 1)] = make_float4(t0.w, t1.x, t1.y,
                    0.5f * (t0.w * t0.w + t1.x * t1.x + t1.y * t1.y));
                sm.knn.sp4[SWZ(p0 + 2)] = make_float4(t1.z, t1.w, t2.x,
                    0.5f * (t1.z * t1.z + t1.w * t1.w + t2.x * t2.x));
                sm.knn.sp4[SWZ(p0 + 3)] = make_float4(t2.y, t2.z, t2.w,
                    0.5f * (t2.y * t2.y + t2.z * t2.z + t2.w * t2.w));
            }
            __syncthreads();
            #pragma unroll
            for (int jj = 0; jj < KSLAB / 64; ++jj) {
                const float4 P = sm.knn.sp4[jj * 64 + cs];
                #pragma unroll
                for (int i = 0; i < 8; ++i) {
                    const float s = fmaf(P.x, axq[i], fmaf(P.y, ayq[i], fmaf(P.z, azq[i], P.w)));
                    cm[i] = fminf(cm[i], s);
                }
            }
        }

        float T[8];
        #pragma unroll
        for (int i = 0; i < 8; ++i) {
            float v = cm[i], h;
            #pragma unroll
            for (int t = 0; t < 7; ++t) {
                h = v;
                h = fminf(h, __shfl_xor(h, 32, 64));
                h = fminf(h, __shfl_xor(h, 16, 64));
                h = fminf(h, __shfl_xor(h, 8, 64));
                h = fminf(h, __shfl_xor(h, 4, 64));
                h = fminf(h, __shfl_xor(h, 2, 64));
                h = fminf(h, __shfl_xor(h, 1, 64));
                T[i] = h;
                if (v == h) v = INFf;   // >=7 chunks knocked out => >=7 pts <= T
            }
        }

        for (int slab = 0; slab < Nn / KSLAB; ++slab) {
            __syncthreads();
            if (tid < 128) {
                float4 t0 = t4[384 * slab + tid * 3 + 0];
                float4 t1 = t4[384 * slab + tid * 3 + 1];
                float4 t2 = t4[384 * slab + tid * 3 + 2];
                const int p0 = tid * 4;
                sm.knn.sp4[SWZ(p0 + 0)] = make_float4(t0.x, t0.y, t0.z,
                    0.5f * (t0.x * t0.x + t0.y * t0.y + t0.z * t0.z));
                sm.knn.sp4[SWZ(p0 + 1)] = make_float4(t0.w, t1.x, t1.y,
                    0.5f * (t0.w * t0.w + t1.x * t1.x + t1.y * t1.y));
                sm.knn.sp4[SWZ(p0 + 2)] = make_float4(t1.z, t1.w, t2.x,
                    0.5f * (t1.z * t1.z + t1.w * t1.w + t2.x * t2.x));
                sm.knn.sp4[SWZ(p0 + 3)] = make_float4(t2.y, t2.z, t2.w,
                    0.5f * (t2.y * t2.y + t2.z * t2.z + t2.w * t2.w));
            }
            __syncthreads();
            #pragma unroll
            for (int jj = 0; jj < KSLAB / 64; ++jj) {
                const float4 P = sm.knn.sp4[jj * 64 + cs];
                const int p = slab * KSLAB + jj * 64 + c;
                #pragma unroll
                for (int i = 0; i < 8; ++i) {
                    const float s = fmaf(P.x, axq[i], fmaf(P.y, ayq[i], fmaf(P.z, azq[i], P.w)));
                    if (s <= T[i]) {
                        const int slot = wid * 8 + i;
                        const int pos = atomicAdd(&sm.knn.cnt[slot], 1);
                        if (pos < KCAP)
                            sm.knn.cand[slot][pos] =
                                ((unsigned long long)ordkey(s) << 32) | (unsigned)p;
                    }
                }
            }
        }
        __syncthreads();

        if (tid < 32) {
            const int q = kb * 32 + tid;
            const int m = min(sm.knn.cnt[tid], KCAP);
            unsigned long long l0 = ~0ULL, l1 = ~0ULL, l2 = ~0ULL, l3 = ~0ULL,
                               l4 = ~0ULL, l5 = ~0ULL, l6 = ~0ULL;
            for (int t = 0; t < m; ++t) {
                const unsigned long long key = sm.knn.cand[tid][t];
                if (key < l6) {
                    l6 = key;
                    if (l6 < l5) { auto tt = l5; l5 = l6; l6 = tt; }
                    if (l5 < l4) { auto tt = l4; l4 = l5; l5 = tt; }
                    if (l4 < l3) { auto tt = l3; l3 = l4; l4 = tt; }
                    if (l3 < l2) { auto tt = l2; l2 = l3; l3 = tt; }
                    if (l2 < l1) { auto tt = l1; l1 = l2; l2 = tt; }
                    if (l1 < l0) { auto tt = l0; l0 = l1; l1 = tt; }
                }
            }
            int nb[6] = { (int)(unsigned)l1, (int)(unsigned)l2, (int)(unsigned)l3,
                          (int)(unsigned)l4, (int)(unsigned)l5, (int)(unsigned)l6 };
            float s = 0.0f;
            #pragma unroll
            for (int k = 0; k < 6; ++k) {
                const int j = nb[k];
                #pragma unroll
                for (int bb = 0; bb < Bb; ++bb) {
                    const float* dn = disp + ((long)bb * Nn + q) * 3;
                    const float* dj = disp + ((long)bb * Nn + j) * 3;
                    const float ddx = dj[0] - dn[0];
                    const float ddy = dj[1] - dn[1];
                    const float ddz = dj[2] - dn[2];
                    s += ddx * ddx + ddy * ddy + ddz * ddz;
                }
            }
            sm.knn.part[tid] = s;
        }
        __syncthreads();
        if (tid == 0) {
            float tot = 0.0f;
            #pragma unroll
            for (int i = 0; i < 32; ++i) tot += sm.knn.part[i];
            atomicAdd(&acc[3], tot);
        }
    }
}

// ---- fused tail: reductions + last-block finalize ----
__global__ __launch_bounds__(256) void tail_reduce_kernel(
    const float* __restrict__ minArr, const float* __restrict__ pm,
    const float* __restrict__ tm, const float* __restrict__ dp,
    float* __restrict__ acc, float* __restrict__ out) {
    const int tid = threadIdx.x;
    const int stride = gridDim.x * blockDim.x;
    float sc = 0.0f, sm = 0.0f, sd = 0.0f;
    for (int i = blockIdx.x * blockDim.x + tid; i < 2 * Bb * Nn; i += stride) {
        sc += sqrtf(fmaxf(minArr[i], 1e-12f));
    }
    for (int i = blockIdx.x * blockDim.x + tid; i < Bb * Nn * 4; i += stride) {
        float d = pm[i] - tm[i];
        sm += d * d;
    }
    for (int i = blockIdx.x * blockDim.x + tid; i < Bb * Nn * 3; i += stride) {
        float v = dp[i];
        sd += v * v;
    }
    __shared__ float r0[256], r1[256], r2[256];
    r0[tid] = sc; r1[tid] = sm; r2[tid] = sd;
    __syncthreads();
    for (int w = 128; w > 0; w >>= 1) {
        if (tid < w) { r0[tid] += r0[tid + w]; r1[tid] += r1[tid + w]; r2[tid] += r2[tid + w]; }
        __syncthreads();
    }
    if (tid == 0) {
        atomicAdd(&acc[0], r0[0]);
        atomicAdd(&acc[1], r1[0]);
        atomicAdd(&acc[2], r2[0]);
        __threadfence();
        const unsigned done = atomicAdd((unsigned*)&acc[7], 1u);
        if (done == (unsigned)(gridDim.x - 1)) {
            const float c0 = atomicAdd(&acc[0], 0.0f);
            const float c1 = atomicAdd(&acc[1], 0.0f);
            const float c2 = atomicAdd(&acc[2], 0.0f);
            const float c3 = atomicAdd(&acc[3], 0.0f);
            const float cd  = c0 / (2.0f * Bb * Nn);
            const float mat = c1 / (float)(Bb * Nn * 4);
            const float dr  = c2 / (float)(Bb * Nn * 3);
            const float smo = c3 / (float)(Bb * Nn * KNB * 3);
            out[0] = 1.0f * cd + 0.1f * mat + 0.01f * dr + 0.005f * smo;
        }
    }
}

}  // namespace

extern "C" void kernel_launch(void* const* d_in, const int* in_sizes, int n_in,
                              void* d_out, int out_size, void* d_ws, size_t ws_size,
                              hipStream_t stream) {
    const float* pred_disp  = (const float*)d_in[0];
    const float* pred_mat   = (const float*)d_in[1];
    const float* target_pos = (const float*)d_in[2];
    const float* target_mat = (const float*)d_in[3];
    const float* tmpl       = (const float*)d_in[4];

    float* ws = (float*)d_ws;
    unsigned* minArr = (unsigned*)ws;         // 2*B*N mins (atomicMin merge of 8 eighths)
    float* acc = ws + 2 * Bb * Nn;            // 8 accumulators (acc[7] = block counter)

    init_ws_kernel<<<(2 * Bb * Nn) / 256, 256, 0, stream>>>(minArr, acc);

    fat_kernel<<<KNN_BLOCKS + CH_BLOCKS, 256, 0, stream>>>(
        pred_disp, tmpl, target_pos, minArr, acc);

    tail_reduce_kernel<<<TAIL_BLOCKS, 256, 0, stream>>>(
        (const float*)minArr, pred_mat, target_mat, pred_disp, acc, (float*)d_out);
}

// Round 16
// 67.755 us; speedup vs baseline: 1.7546x; 1.7546x over previous
//
#include <hip/hip_runtime.h>

namespace {

typedef _Float16 half8 __attribute__((ext_vector_type(8)));
typedef float f32x16 __attribute__((ext_vector_type(16)));

constexpr int Bb = 4, Nn = 8192, KNB = 6;
constexpr int KSLAB = 1024;                  // knn slab points (16 KB)
constexpr int KCAP = 64;                     // knn candidate slots per query
constexpr int KNN_BLOCKS = Nn / 16;          // 512 (16 queries per block, 4 per wave)
constexpr int CH_BLOCKS = 1024;              // 8 bd * 8 eighths * 16 qgroups(512 queries)
constexpr int CH_CHUNK = 1024;               // points per chamfer block
constexpr int TAIL_BLOCKS = 128;

// XOR bank swizzle: bijective, even bank-group spread for writes (p=4t+k),
// chamfer reads (p=32tt+l) and knn reads (p=64jj+c).  group(slot)=slot mod 8.
#define SWZ(p) ((p) ^ ((((p) >> 3) & 7)))

union SMemU {
    half8 aF[CH_CHUNK];                      // 16 KB chamfer frags (swizzled)
    struct {
        float4 sp4[KSLAB];                   // 16 KB (swizzled)
        unsigned long long cand[16][KCAP];   // 8 KB
        int cnt[16];
        float part[16];
    } knn;                                   // ~24.7 KB
};

__device__ inline unsigned ordkey(float f) {
    unsigned b = __float_as_uint(f);
    return b ^ (unsigned)(((int)b >> 31) | 0x80000000);
}

__device__ inline half8 zero8() {
    half8 v;
    #pragma unroll
    for (int i = 0; i < 8; ++i) v[i] = (_Float16)0;
    return v;
}

// Consistent single-f16 scheme (kg0 slots only; kg1 lanes zero on B side):
//   acc = -p̂·q̂ + |p̂|²/2 ; d2 = |q̂|² + 2·acc = |q̂-p̂|² ± ~7e-6 (clamped >= 0)
__device__ inline half8 a_frag(float x, float y, float z) {
    _Float16 hx = (_Float16)x, hy = (_Float16)y, hz = (_Float16)z;
    const float xr = (float)hx, yr = (float)hy, zr = (float)hz;
    const float pp5 = 0.5f * (xr * xr + yr * yr + zr * zr);
    _Float16 ph = (_Float16)pp5, pl = (_Float16)(pp5 - (float)ph);
    half8 v;
    v[0] = -hx; v[1] = -hy; v[2] = -hz; v[3] = ph; v[4] = pl;
    v[5] = (_Float16)0; v[6] = (_Float16)0; v[7] = (_Float16)0;
    return v;
}
__device__ inline half8 b_frag(float x, float y, float z) {
    _Float16 hx = (_Float16)x, hy = (_Float16)y, hz = (_Float16)z;
    half8 v;
    v[0] = hx; v[1] = hy; v[2] = hz; v[3] = (_Float16)1; v[4] = (_Float16)1;
    v[5] = (_Float16)0; v[6] = (_Float16)0; v[7] = (_Float16)0;
    return v;
}

// ---------------- init: mins -> +inf, accumulators -> 0 ----------------
__global__ void init_ws_kernel(unsigned* __restrict__ minArr, float* __restrict__ acc) {
    int i = blockIdx.x * blockDim.x + threadIdx.x;
    if (i < 2 * Bb * Nn) minArr[i] = 0x7f800000u;
    if (i < 8) acc[i] = 0.0f;
}

// ------- fat kernel: knn blocks [0,512) + chamfer-mfma eighth-blocks [512,1536) ----
__global__ __launch_bounds__(256, 6) void fat_kernel(
    const float* __restrict__ disp, const float* __restrict__ tmpl,
    const float* __restrict__ targ, unsigned* __restrict__ outMin,
    float* __restrict__ acc) {
    __shared__ SMemU sm;
    const int tid = threadIdx.x;

    if (blockIdx.x >= KNN_BLOCKS) {
        // ===== chamfer via MFMA: 512 queries (4 groups/wave), 1024 points per block ====
        const int cb = (int)blockIdx.x - KNN_BLOCKS;   // 0..1023
        const int qbase = (cb & 15) * 512;
        const int eighth = (cb >> 4) & 7;
        const int bd = cb >> 7;                        // 0..7
        const int dir = bd & 1, b = bd >> 1;
        const int lane = tid & 63, w = tid >> 6;
        const int l31 = lane & 31, kg = lane >> 5;

        float qq[4];
        half8 Bf[4];
        #pragma unroll
        for (int j = 0; j < 4; ++j) {
            const int q = qbase + w * 128 + j * 32 + l31;
            const long e = ((long)b * Nn + q) * 3;
            float x, y, z;
            if (dir == 0) {   // queries = pred
                x = tmpl[e] + disp[e]; y = tmpl[e+1] + disp[e+1]; z = tmpl[e+2] + disp[e+2];
            } else {          // queries = targ
                x = targ[e]; y = targ[e+1]; z = targ[e+2];
            }
            _Float16 hx = (_Float16)x, hy = (_Float16)y, hz = (_Float16)z;
            const float xr = (float)hx, yr = (float)hy, zr = (float)hz;
            qq[j] = xr * xr + yr * yr + zr * zr;
            Bf[j] = (kg == 0) ? b_frag(x, y, z) : zero8();
        }

        float run[4] = {1e38f, 1e38f, 1e38f, 1e38f};
        const f32x16 zc = {0.f, 0.f, 0.f, 0.f, 0.f, 0.f, 0.f, 0.f,
                           0.f, 0.f, 0.f, 0.f, 0.f, 0.f, 0.f, 0.f};

        {
            const int pbase = eighth * CH_CHUNK;
            {
                // thread stages 4 consecutive points via 3x float4; swizzled LDS write
                const long fbase = ((long)b * Nn + pbase) * 3;   // float4-aligned
                const float4* s4 = (const float4*)((dir == 0 ? targ : tmpl) + fbase);
                float4 t0 = s4[tid * 3 + 0], t1 = s4[tid * 3 + 1], t2 = s4[tid * 3 + 2];
                if (dir == 1) {   // points = pred = tmpl + disp
                    const float4* d4 = (const float4*)(disp + fbase);
                    float4 u0 = d4[tid * 3 + 0], u1 = d4[tid * 3 + 1], u2 = d4[tid * 3 + 2];
                    t0.x += u0.x; t0.y += u0.y; t0.z += u0.z; t0.w += u0.w;
                    t1.x += u1.x; t1.y += u1.y; t1.z += u1.z; t1.w += u1.w;
                    t2.x += u2.x; t2.y += u2.y; t2.z += u2.z; t2.w += u2.w;
                }
                const int p0 = tid * 4;
                sm.aF[SWZ(p0 + 0)] = a_frag(t0.x, t0.y, t0.z);
                sm.aF[SWZ(p0 + 1)] = a_frag(t0.w, t1.x, t1.y);
                sm.aF[SWZ(p0 + 2)] = a_frag(t1.z, t1.w, t2.x);
                sm.aF[SWZ(p0 + 3)] = a_frag(t2.y, t2.z, t2.w);
            }
            __syncthreads();
            #pragma unroll 2
            for (int tt = 0; tt < 32; ++tt) {
                const int pr = tt * 32 + l31;
                const half8 a = sm.aF[SWZ(pr)];   // lanes l,l+32 broadcast (x0 on kg1)
                #pragma unroll
                for (int j = 0; j < 4; ++j) {
                    f32x16 c = __builtin_amdgcn_mfma_f32_32x32x16_f16(a, Bf[j], zc, 0, 0, 0);
                    #pragma unroll
                    for (int r = 0; r < 16; r += 2)
                        run[j] = fminf(run[j], fminf(c[r], c[r + 1]));  // -> v_min3_f32
                }
            }
        }

        #pragma unroll
        for (int j = 0; j < 4; ++j)
            run[j] = fminf(run[j], __shfl_xor(run[j], 32, 64));
        if (lane < 32) {
            const long base = ((long)dir * Bb + b) * Nn;
            #pragma unroll
            for (int j = 0; j < 4; ++j) {
                const int q = qbase + w * 128 + j * 32 + l31;
                const float d2 = fmaxf(fmaf(2.0f, run[j], qq[j]), 0.0f);
                atomicMin(&outMin[base + q], __float_as_uint(d2));
            }
        }
    } else {
        // ================= knn + smooth (round-14 verbatim: 4 queries/lane) ===========
        const int kb = blockIdx.x;
        const int lane = tid & 63;
        const int wid = tid >> 6;
        const int c = lane;
        const int cs = c ^ (c >> 3);               // swizzled lane base: slot = jj*64 + cs

        const int qbase = kb * 16 + wid * 4;
        float axq[4], ayq[4], azq[4];
        #pragma unroll
        for (int i = 0; i < 4; ++i) {
            axq[i] = -tmpl[(qbase + i) * 3 + 0];
            ayq[i] = -tmpl[(qbase + i) * 3 + 1];
            azq[i] = -tmpl[(qbase + i) * 3 + 2];
        }
        const float INFf = __uint_as_float(0x7f800000u);

        if (tid < 16) sm.knn.cnt[tid] = 0;

        float cm[4];
        #pragma unroll
        for (int i = 0; i < 4; ++i) cm[i] = INFf;

        const float4* t4 = (const float4*)tmpl;   // template[0]

        for (int slab = 0; slab < Nn / KSLAB; ++slab) {
            __syncthreads();
            {
                float4 t0 = t4[768 * slab + tid * 3 + 0];
                float4 t1 = t4[768 * slab + tid * 3 + 1];
                float4 t2 = t4[768 * slab + tid * 3 + 2];
                const int p0 = tid * 4;
                sm.knn.sp4[SWZ(p0 + 0)] = make_float4(t0.x, t0.y, t0.z,
                    0.5f * (t0.x * t0.x + t0.y * t0.y + t0.z * t0.z));
                sm.knn.sp4[SWZ(p0 + 1)] = make_float4(t0.w, t1.x, t1.y,
                    0.5f * (t0.w * t0.w + t1.x * t1.x + t1.y * t1.y));
                sm.knn.sp4[SWZ(p0 + 2)] = make_float4(t1.z, t1.w, t2.x,
                    0.5f * (t1.z * t1.z + t1.w * t1.w + t2.x * t2.x));
                sm.knn.sp4[SWZ(p0 + 3)] = make_float4(t2.y, t2.z, t2.w,
                    0.5f * (t2.y * t2.y + t2.z * t2.z + t2.w * t2.w));
            }
            __syncthreads();
            #pragma unroll 2
            for (int jj = 0; jj < KSLAB / 64; jj += 2) {
                const float4 P0 = sm.knn.sp4[(jj + 0) * 64 + cs];
                const float4 P1 = sm.knn.sp4[(jj + 1) * 64 + cs];
                #pragma unroll
                for (int i = 0; i < 4; ++i) {
                    const float s0 = fmaf(P0.x, axq[i], fmaf(P0.y, ayq[i], fmaf(P0.z, azq[i], P0.w)));
                    const float s1 = fmaf(P1.x, axq[i], fmaf(P1.y, ayq[i], fmaf(P1.z, azq[i], P1.w)));
                    cm[i] = fminf(fminf(cm[i], s0), s1);
                }
            }
        }

        float T[4];
        #pragma unroll
        for (int i = 0; i < 4; ++i) {
            float v = cm[i], h;
            #pragma unroll
            for (int t = 0; t < 7; ++t) {
                h = v;
                h = fminf(h, __shfl_xor(h, 32, 64));
                h = fminf(h, __shfl_xor(h, 16, 64));
                h = fminf(h, __shfl_xor(h, 8, 64));
                h = fminf(h, __shfl_xor(h, 4, 64));
                h = fminf(h, __shfl_xor(h, 2, 64));
                h = fminf(h, __shfl_xor(h, 1, 64));
                T[i] = h;
                if (v == h) v = INFf;   // >=7 chunks knocked out => >=7 pts <= T
            }
        }

        for (int slab = 0; slab < Nn / KSLAB; ++slab) {
            __syncthreads();
            {
                float4 t0 = t4[768 * slab + tid * 3 + 0];
                float4 t1 = t4[768 * slab + tid * 3 + 1];
                float4 t2 = t4[768 * slab + tid * 3 + 2];
                const int p0 = tid * 4;
                sm.knn.sp4[SWZ(p0 + 0)] = make_float4(t0.x, t0.y, t0.z,
                    0.5f * (t0.x * t0.x + t0.y * t0.y + t0.z * t0.z));
                sm.knn.sp4[SWZ(p0 + 1)] = make_float4(t0.w, t1.x, t1.y,
                    0.5f * (t0.w * t0.w + t1.x * t1.x + t1.y * t1.y));
                sm.knn.sp4[SWZ(p0 + 2)] = make_float4(t1.z, t1.w, t2.x,
                    0.5f * (t1.z * t1.z + t1.w * t1.w + t2.x * t2.x));
                sm.knn.sp4[SWZ(p0 + 3)] = make_float4(t2.y, t2.z, t2.w,
                    0.5f * (t2.y * t2.y + t2.z * t2.z + t2.w * t2.w));
            }
            __syncthreads();
            #pragma unroll 2
            for (int jj = 0; jj < KSLAB / 64; ++jj) {
                const float4 P = sm.knn.sp4[jj * 64 + cs];
                const int p = slab * KSLAB + jj * 64 + c;
                #pragma unroll
                for (int i = 0; i < 4; ++i) {
                    const float s = fmaf(P.x, axq[i], fmaf(P.y, ayq[i], fmaf(P.z, azq[i], P.w)));
                    if (s <= T[i]) {
                        const int slot = wid * 4 + i;
                        const int pos = atomicAdd(&sm.knn.cnt[slot], 1);
                        if (pos < KCAP)
                            sm.knn.cand[slot][pos] =
                                ((unsigned long long)ordkey(s) << 32) | (unsigned)p;
                    }
                }
            }
        }
        __syncthreads();

        if (tid < 16) {
            const int q = kb * 16 + tid;
            const int m = min(sm.knn.cnt[tid], KCAP);
            unsigned long long l0 = ~0ULL, l1 = ~0ULL, l2 = ~0ULL, l3 = ~0ULL,
                               l4 = ~0ULL, l5 = ~0ULL, l6 = ~0ULL;
            for (int t = 0; t < m; ++t) {
                const unsigned long long key = sm.knn.cand[tid][t];
                if (key < l6) {
                    l6 = key;
                    if (l6 < l5) { auto tt = l5; l5 = l6; l6 = tt; }
                    if (l5 < l4) { auto tt = l4; l4 = l5; l5 = tt; }
                    if (l4 < l3) { auto tt = l3; l3 = l4; l4 = tt; }
                    if (l3 < l2) { auto tt = l2; l2 = l3; l3 = tt; }
                    if (l2 < l1) { auto tt = l1; l1 = l2; l2 = tt; }
                    if (l1 < l0) { auto tt = l0; l0 = l1; l1 = tt; }
                }
            }
            int nb[6] = { (int)(unsigned)l1, (int)(unsigned)l2, (int)(unsigned)l3,
                          (int)(unsigned)l4, (int)(unsigned)l5, (int)(unsigned)l6 };
            float s = 0.0f;
            #pragma unroll
            for (int k = 0; k < 6; ++k) {
                const int j = nb[k];
                #pragma unroll
                for (int bb = 0; bb < Bb; ++bb) {
                    const float* dn = disp + ((long)bb * Nn + q) * 3;
                    const float* dj = disp + ((long)bb * Nn + j) * 3;
                    const float ddx = dj[0] - dn[0];
                    const float ddy = dj[1] - dn[1];
                    const float ddz = dj[2] - dn[2];
                    s += ddx * ddx + ddy * ddy + ddz * ddz;
                }
            }
            sm.knn.part[tid] = s;
        }
        __syncthreads();
        if (tid == 0) {
            float tot = 0.0f;
            #pragma unroll
            for (int i = 0; i < 16; ++i) tot += sm.knn.part[i];
            atomicAdd(&acc[3], tot);
        }
    }
}

// ---- fused tail: reductions + last-block finalize ----
__global__ __launch_bounds__(256) void tail_reduce_kernel(
    const float* __restrict__ minArr, const float* __restrict__ pm,
    const float* __restrict__ tm, const float* __restrict__ dp,
    float* __restrict__ acc, float* __restrict__ out) {
    const int tid = threadIdx.x;
    const int stride = gridDim.x * blockDim.x;
    float sc = 0.0f, sm = 0.0f, sd = 0.0f;
    for (int i = blockIdx.x * blockDim.x + tid; i < 2 * Bb * Nn; i += stride) {
        sc += sqrtf(fmaxf(minArr[i], 1e-12f));
    }
    for (int i = blockIdx.x * blockDim.x + tid; i < Bb * Nn * 4; i += stride) {
        float d = pm[i] - tm[i];
        sm += d * d;
    }
    for (int i = blockIdx.x * blockDim.x + tid; i < Bb * Nn * 3; i += stride) {
        float v = dp[i];
        sd += v * v;
    }
    __shared__ float r0[256], r1[256], r2[256];
    r0[tid] = sc; r1[tid] = sm; r2[tid] = sd;
    __syncthreads();
    for (int w = 128; w > 0; w >>= 1) {
        if (tid < w) { r0[tid] += r0[tid + w]; r1[tid] += r1[tid + w]; r2[tid] += r2[tid + w]; }
        __syncthreads();
    }
    if (tid == 0) {
        atomicAdd(&acc[0], r0[0]);
        atomicAdd(&acc[1], r1[0]);
        atomicAdd(&acc[2], r2[0]);
        __threadfence();
        const unsigned done = atomicAdd((unsigned*)&acc[7], 1u);
        if (done == (unsigned)(gridDim.x - 1)) {
            const float c0 = atomicAdd(&acc[0], 0.0f);
            const float c1 = atomicAdd(&acc[1], 0.0f);
            const float c2 = atomicAdd(&acc[2], 0.0f);
            const float c3 = atomicAdd(&acc[3], 0.0f);
            const float cd  = c0 / (2.0f * Bb * Nn);
            const float mat = c1 / (float)(Bb * Nn * 4);
            const float dr  = c2 / (float)(Bb * Nn * 3);
            const float smo = c3 / (float)(Bb * Nn * KNB * 3);
            out[0] = 1.0f * cd + 0.1f * mat + 0.01f * dr + 0.005f * smo;
        }
    }
}

}  // namespace

extern "C" void kernel_launch(void* const* d_in, const int* in_sizes, int n_in,
                              void* d_out, int out_size, void* d_ws, size_t ws_size,
                              hipStream_t stream) {
    const float* pred_disp  = (const float*)d_in[0];
    const float* pred_mat   = (const float*)d_in[1];
    const float* target_pos = (const float*)d_in[2];
    const float* target_mat = (const float*)d_in[3];
    const float* tmpl       = (const float*)d_in[4];

    float* ws = (float*)d_ws;
    unsigned* minArr = (unsigned*)ws;         // 2*B*N mins (atomicMin merge of 8 eighths)
    float* acc = ws + 2 * Bb * Nn;            // 8 accumulators (acc[7] = block counter)

    init_ws_kernel<<<(2 * Bb * Nn) / 256, 256, 0, stream>>>(minArr, acc);

    fat_kernel<<<KNN_BLOCKS + CH_BLOCKS, 256, 0, stream>>>(
        pred_disp, tmpl, target_pos, minArr, acc);

    tail_reduce_kernel<<<TAIL_BLOCKS, 256, 0, stream>>>(
        (const float*)minArr, pred_mat, target_mat, pred_disp, acc, (float*)d_out);
}